// Round 4
// baseline (686.117 us; speedup 1.0000x reference)
//
#include <hip/hip_runtime.h>
#include <stdint.h>

// UpsampleUpFIRDn: 2x upsample + 4x4 FIR (upfirdn2d, up=2, down=1, pad0=2, pad1=1)
// x: (8,64,256,256) FP32 -> out: (8,64,512,512) FP32; kernel: 4x4 FP32 (pre-scaled by factor^2)
//
// R1/R2 post-mortems (prev session): input and output are both FP32.
// R3 theory: timed region = ~340us poison fill (fixed) + kernel. Row-pair restructure +
// NT stores: 680 -> 616 us (kernel ~340 -> ~276 us). Confirmed fill floor (top-5 all fills).
// R5 theory: residual is VMEM-issue/L1-transaction bound, not BW: the 4 strided scalar
// edge loads each cost as many L1 128B transactions as the full dwordx4 row load (stride-16B
// gather spanning the same 1KB), tripling load-side L1 traffic for data the wave already
// holds. Replace them with cross-lane shuffles: rowX[c0-1] = lane t-1's .w, rowX[c0+4] =
// lane t+1's .x. VMEM loads/thread 6 -> 2.
// R6: R5 bench never ran (GPU acquisition timeout) — resubmitting identical kernel.
//
// Parity decomposition (verified analytically vs the flip+dilated-conv reference):
//   output row y: py=y&1, i=y>>1
//     py=0: taps (row i-1, krow 3), (row i, krow 1)
//     py=1: taps (row i,   krow 2), (row i+1, krow 0)
//   same mapping for columns.
//
// Row-pair structure: output rows 2q+1 (py=1, i=q) and 2q+2 (py=0, i=q+1) both read
// ONLY input rows (q, q+1):
//   y1 = 2q+1 : (row q, krow 2), (row q+1, krow 0)
//   y2 = 2q+2 : (row q, krow 3), (row q+1, krow 1)
// One wave = one pair q in [-1, 255]; q=-1 emits only y=0, q=255 emits only y=511.

#define IN_H 256
#define IN_W 256
#define OUT_H 512
#define OUT_W 512

typedef float f4 __attribute__((ext_vector_type(4)));

__global__ __launch_bounds__(256) void upfirdn2x_kernel(
    const float* __restrict__ x,    // [nch][256][256]
    const float* __restrict__ k2,   // [4][4]
    float* __restrict__ out)        // [nch][512][512]
{
    const int t  = threadIdx.x & 63;   // 64 threads across the row; 8 output cols each
    const int ty = threadIdx.x >> 6;   // 4 row-pairs per block; wave == one pair (uniform branches)
    const int q  = blockIdx.x * 4 + ty - 1;   // input-row-pair index, -1..255
    if (q >= IN_H) return;                    // tail waves of the last x-block
    const int ch = blockIdx.y;

    const bool vA = (q >= 0);          // row q valid
    const bool vB = (q + 1 < IN_H);    // row q+1 valid

    const float* xc   = x + (size_t)ch * (IN_H * IN_W);
    const float* rowA = xc + (size_t)(vA ? q     : 0) * IN_W;
    const float* rowB = xc + (size_t)(vB ? q + 1 : 0) * IN_W;

    const int c0 = 4 * t;  // input cols c0..c0+3 (16B-aligned)
    const f4 a4 = *reinterpret_cast<const f4*>(rowA + c0);
    const f4 b4 = *reinterpret_cast<const f4*>(rowB + c0);

    // halo via cross-lane shuffle: lane t-1 holds rowX[c0-1] in .w, lane t+1 holds
    // rowX[c0+4] in .x. Image-edge lanes (t==0 / t==63) are zero-padded.
    const float hAl = __shfl_up(a4.w, 1);
    const float hBl = __shfl_up(b4.w, 1);
    const float hAr = __shfl_down(a4.x, 1);
    const float hBr = __shfl_down(b4.x, 1);

    // input cols c0-1 .. c0+4, zero-padded at image edges
    float cA[6], cB[6];
    cA[0] = (t > 0)  ? hAl : 0.0f;
    cB[0] = (t > 0)  ? hBl : 0.0f;
    cA[5] = (t < 63) ? hAr : 0.0f;
    cB[5] = (t < 63) ? hBr : 0.0f;
    cA[1] = a4.x; cA[2] = a4.y; cA[3] = a4.z; cA[4] = a4.w;
    cB[1] = b4.x; cB[2] = b4.y; cB[3] = b4.z; cB[4] = b4.w;

    if (!vA) {   // wave-uniform, only the q=-1 edge pair
#pragma unroll
        for (int c = 0; c < 6; ++c) cA[c] = 0.0f;
    }
    if (!vB) {   // wave-uniform, only the q=255 edge pair
#pragma unroll
        for (int c = 0; c < 6; ++c) cB[c] = 0.0f;
    }

    // all 16 weights, wave-uniform (compiler emits s_load)
    float kw[16];
#pragma unroll
    for (int i = 0; i < 16; ++i) kw[i] = k2[i];

    // y1 = 2q+1 : A-row weights = krow 2 (kw[8..11]),  B-row = krow 0 (kw[0..3])
    // y2 = 2q+2 : A-row weights = krow 3 (kw[12..15]), B-row = krow 1 (kw[4..7])
    float o1[8], o2[8];
#pragma unroll
    for (int u = 0; u < 8; ++u) {
        const int j = u >> 1;
        if ((u & 1) == 0) {
            // px=0: cols (j-1, kcol 3), (j, kcol 1)
            o1[u] = kw[8+3]*cA[j]  + kw[8+1]*cA[j+1]  + kw[0+3]*cB[j]  + kw[0+1]*cB[j+1];
            o2[u] = kw[12+3]*cA[j] + kw[12+1]*cA[j+1] + kw[4+3]*cB[j]  + kw[4+1]*cB[j+1];
        } else {
            // px=1: cols (j, kcol 2), (j+1, kcol 0)
            o1[u] = kw[8+2]*cA[j+1]  + kw[8+0]*cA[j+2]  + kw[0+2]*cB[j+1] + kw[0+0]*cB[j+2];
            o2[u] = kw[12+2]*cA[j+1] + kw[12+0]*cA[j+2] + kw[4+2]*cB[j+1] + kw[4+0]*cB[j+2];
        }
    }

    float* ob = out + (size_t)ch * (OUT_H * OUT_W);
    if (vA) {  // y1 = 2q+1 in [1, 511]
        float* op = ob + (size_t)(2 * q + 1) * OUT_W + 8 * t;
        f4 s0; s0.x = o1[0]; s0.y = o1[1]; s0.z = o1[2]; s0.w = o1[3];
        f4 s1; s1.x = o1[4]; s1.y = o1[5]; s1.z = o1[6]; s1.w = o1[7];
        __builtin_nontemporal_store(s0, reinterpret_cast<f4*>(op));
        __builtin_nontemporal_store(s1, reinterpret_cast<f4*>(op + 4));
    }
    if (vB) {  // y2 = 2q+2 in [0, 510]
        float* op = ob + (size_t)(2 * q + 2) * OUT_W + 8 * t;
        f4 s0; s0.x = o2[0]; s0.y = o2[1]; s0.z = o2[2]; s0.w = o2[3];
        f4 s1; s1.x = o2[4]; s1.y = o2[5]; s1.z = o2[6]; s1.w = o2[7];
        __builtin_nontemporal_store(s0, reinterpret_cast<f4*>(op));
        __builtin_nontemporal_store(s1, reinterpret_cast<f4*>(op + 4));
    }
}

extern "C" void kernel_launch(void* const* d_in, const int* in_sizes, int n_in,
                              void* d_out, int out_size, void* d_ws, size_t ws_size,
                              hipStream_t stream) {
    const float* x  = (const float*)d_in[0];   // fp32, 8*64*256*256
    const float* k2 = (const float*)d_in[1];   // fp32, 16 elems
    float* out = (float*)d_out;                // fp32, 8*64*512*512

    const int nch = in_sizes[0] / (IN_H * IN_W);  // 8*64 = 512
    const int npairs = IN_H + 1;                  // q = -1 .. 255
    dim3 block(256);
    dim3 grid((npairs + 3) / 4, nch);             // 65 x 512
    upfirdn2x_kernel<<<grid, block, 0, stream>>>(x, k2, out);
}

// Round 5
// 597.044 us; speedup vs baseline: 1.1492x; 1.1492x over previous
//
#include <hip/hip_runtime.h>
#include <stdint.h>

// UpsampleUpFIRDn: 2x upsample + 4x4 FIR (upfirdn2d, up=2, down=1, pad0=2, pad1=1)
// x: (8,64,256,256) FP32 -> out: (8,64,512,512) FP32; kernel: 4x4 FP32 (pre-scaled by factor^2)
//
// Journal:
// R3: row-pair restructure + NT stores: 680 -> 616 us (kernel ~340 -> ~276). Fill floor ~340us.
// R5/R6: shuffle-halo (ds_bpermute): 686 us — REGRESSION, reverted. Scalar halo loads were
//   L1-hot and cheap; shuffles put LDS-pipe ops on the critical path.
// R7 (this): dense wave-level access mapping. Old store pattern (lane t -> cols 8t, 8t+4)
//   was half-dense across the wave: each f4 store touched 16x128B lines (stride-32B over a
//   2KB span). The 6.3TB/s fill kernel stores one dense 1KB block per instr. New mapping:
//   lane t owns output cols {4t..4t+3} and {256+4t..256+4t+3} -> every store instr is a
//   contiguous 1KB wave-block. Loads: per input row per half, one 4B-aligned dwordx4 at
//   col j0-1 (j0=2t+128s) covers all 4 needed cols, dense across the wave. No strided
//   scalar edge loads; image edges via clamped load + selects.
//
// Parity decomposition (verified analytically vs the flip+dilated-conv reference):
//   output row y: py=y&1, i=y>>1
//     py=0: taps (row i-1, krow 3), (row i, krow 1)
//     py=1: taps (row i,   krow 2), (row i+1, krow 0)
//   same mapping for columns: out col c: px=c&1, j=c>>1
//     px=0: taps (col j-1, kcol 3), (col j, kcol 1)
//     px=1: taps (col j,   kcol 2), (col j+1, kcol 0)
//
// Row-pair structure: output rows y1=2q+1 (krowA=2,krowB=0) and y2=2q+2 (krowA=3,krowB=1)
// both read ONLY input rows (q, q+1). One wave = one pair q in [-1,255]; q=-1 emits only
// y=0 (A side zeroed), q=255 emits only y=511 (B side zeroed).

#define IN_H 256
#define IN_W 256
#define OUT_H 512
#define OUT_W 512

typedef float f4 __attribute__((ext_vector_type(4)));

__global__ __launch_bounds__(256) void upfirdn2x_kernel(
    const float* __restrict__ x,    // [nch][256][256]
    const float* __restrict__ k2,   // [4][4]
    float* __restrict__ out)        // [nch][512][512]
{
    const int t  = threadIdx.x & 63;   // lane
    const int ty = threadIdx.x >> 6;   // 4 row-pairs per block; wave == one pair
    const int q  = blockIdx.x * 4 + ty - 1;   // input-row-pair index, -1..255
    if (q >= IN_H) return;                    // tail waves of the last x-block
    const int ch = blockIdx.y;

    const bool vA = (q >= 0);          // row q valid
    const bool vB = (q + 1 < IN_H);    // row q+1 valid

    const float* xc   = x + (size_t)ch * (IN_H * IN_W);
    const float* rowA = xc + (size_t)(vA ? q     : 0) * IN_W;
    const float* rowB = xc + (size_t)(vB ? q + 1 : 0) * IN_W;

    // all 16 weights, wave-uniform
    float kw[16];
#pragma unroll
    for (int i = 0; i < 16; ++i) kw[i] = k2[i];

    float* ob = out + (size_t)ch * (OUT_H * OUT_W);
    float* orow1 = ob + (size_t)(2 * q + 1) * OUT_W;  // y1 (valid iff vA)
    float* orow2 = ob + (size_t)(2 * q + 2) * OUT_W;  // y2 (valid iff vB)

#pragma unroll
    for (int s = 0; s < 2; ++s) {
        // half s covers output cols 256s..256s+255; lane t -> out cols 256s+4t..+3
        // j0 = base input col for this lane-half; need input cols j0-1 .. j0+2
        const int j0 = 2 * t + 128 * s;

        // one dwordx4 load at col j0-1 (4B-aligned), clamped at the image edges:
        //   s==0, t==0 : want cols -1..2  -> load at 0   (cols 0..3),   shift left
        //   s==1, t==63: want cols 253..256 -> load at 252 (cols 252..255), shift right
        int lc = j0 - 1;
        if (s == 0) { if (t == 0)  lc = 0;   }
        else        { if (t == 63) lc = 252; }

        f4 fA, fB;
        __builtin_memcpy(&fA, rowA + lc, 16);
        __builtin_memcpy(&fB, rowB + lc, 16);

        // L[i] = input col j0-1+i (0 outside the image)
        float LA[4], LB[4];
        if (s == 0) {
            const bool e = (t == 0);
            LA[0] = e ? 0.0f : fA.x;  LA[1] = e ? fA.x : fA.y;
            LA[2] = e ? fA.y : fA.z;  LA[3] = e ? fA.z : fA.w;
            LB[0] = e ? 0.0f : fB.x;  LB[1] = e ? fB.x : fB.y;
            LB[2] = e ? fB.y : fB.z;  LB[3] = e ? fB.z : fB.w;
        } else {
            const bool e = (t == 63);
            LA[0] = e ? fA.y : fA.x;  LA[1] = e ? fA.z : fA.y;
            LA[2] = e ? fA.w : fA.z;  LA[3] = e ? 0.0f : fA.w;
            LB[0] = e ? fB.y : fB.x;  LB[1] = e ? fB.z : fB.y;
            LB[2] = e ? fB.w : fB.z;  LB[3] = e ? 0.0f : fB.w;
        }
        if (!vA) {   // wave-uniform, only the q=-1 edge pair
#pragma unroll
            for (int c = 0; c < 4; ++c) LA[c] = 0.0f;
        }
        if (!vB) {   // wave-uniform, only the q=255 edge pair
#pragma unroll
            for (int c = 0; c < 4; ++c) LB[c] = 0.0f;
        }

        // out col 256s+4t+k: px=k&1, j=j0+(k>>1)
        //   k=0: L[0]*kcol3 + L[1]*kcol1
        //   k=1: L[1]*kcol2 + L[2]*kcol0
        //   k=2: L[1]*kcol3 + L[2]*kcol1
        //   k=3: L[2]*kcol2 + L[3]*kcol0
        // y1: A-row krow 2 (kw[8..11]),  B-row krow 0 (kw[0..3])
        // y2: A-row krow 3 (kw[12..15]), B-row krow 1 (kw[4..7])
        f4 o1, o2;
        o1.x = kw[8+3]*LA[0] + kw[8+1]*LA[1] + kw[0+3]*LB[0] + kw[0+1]*LB[1];
        o1.y = kw[8+2]*LA[1] + kw[8+0]*LA[2] + kw[0+2]*LB[1] + kw[0+0]*LB[2];
        o1.z = kw[8+3]*LA[1] + kw[8+1]*LA[2] + kw[0+3]*LB[1] + kw[0+1]*LB[2];
        o1.w = kw[8+2]*LA[2] + kw[8+0]*LA[3] + kw[0+2]*LB[2] + kw[0+0]*LB[3];

        o2.x = kw[12+3]*LA[0] + kw[12+1]*LA[1] + kw[4+3]*LB[0] + kw[4+1]*LB[1];
        o2.y = kw[12+2]*LA[1] + kw[12+0]*LA[2] + kw[4+2]*LB[1] + kw[4+0]*LB[2];
        o2.z = kw[12+3]*LA[1] + kw[12+1]*LA[2] + kw[4+3]*LB[1] + kw[4+1]*LB[2];
        o2.w = kw[12+2]*LA[2] + kw[12+0]*LA[3] + kw[4+2]*LB[2] + kw[4+0]*LB[3];

        const int cb = 256 * s + 4 * t;   // store col base: dense 1KB per wave instr
        if (vA) __builtin_nontemporal_store(o1, reinterpret_cast<f4*>(orow1 + cb));
        if (vB) __builtin_nontemporal_store(o2, reinterpret_cast<f4*>(orow2 + cb));
    }
}

extern "C" void kernel_launch(void* const* d_in, const int* in_sizes, int n_in,
                              void* d_out, int out_size, void* d_ws, size_t ws_size,
                              hipStream_t stream) {
    const float* x  = (const float*)d_in[0];   // fp32, 8*64*256*256
    const float* k2 = (const float*)d_in[1];   // fp32, 16 elems
    float* out = (float*)d_out;                // fp32, 8*64*512*512

    const int nch = in_sizes[0] / (IN_H * IN_W);  // 8*64 = 512
    const int npairs = IN_H + 1;                  // q = -1 .. 255
    dim3 block(256);
    dim3 grid((npairs + 3) / 4, nch);             // 65 x 512
    upfirdn2x_kernel<<<grid, block, 0, stream>>>(x, k2, out);
}